// Round 1
// baseline (181.486 us; speedup 1.0000x reference)
//
#include <hip/hip_runtime.h>
#include <hip/hip_bf16.h>

// Problem constants
#define B_DIM 128
#define T_DIM 2048
#define D_DIM 512
#define H_DIM 8
#define HD_DIM 64
#define CH 16                       // chunks per batch row
#define ROWS_PER_BLOCK (T_DIM / CH) // 128
#define ROWS_PER_WAVE (ROWS_PER_BLOCK / 4) // 32
#define SUBS 64                     // CH * 4 waves = partials per b

// ---------------------------------------------------------------------------
// K0: detect whether mask buffer is 1-byte bool or 4-byte int32.
// Reads first 16384 int32 (= 65536 bytes <= B*T bytes, safe either way).
// If bool-packed, 4 random 0/1 bytes per word give a value >1 with p=7/8.
// ---------------------------------------------------------------------------
__global__ void detect_mask_kernel(const int* __restrict__ mask_as_int,
                                   int* __restrict__ flag) {
    __shared__ int any_big;
    if (threadIdx.x == 0) any_big = 0;
    __syncthreads();
    int local = 0;
    for (int i = threadIdx.x; i < 16384; i += blockDim.x) {
        unsigned v = (unsigned)mask_as_int[i];
        if (v > 1u) local = 1;
    }
    if (local) atomicOr(&any_big, 1);
    __syncthreads();
    if (threadIdx.x == 0) *flag = any_big;  // 1 => byte mask, 0 => int32 mask
}

// ---------------------------------------------------------------------------
// K1: single pass over x. Each wave handles 32 rows for ALL 8 heads with an
// online softmax. Lane i owns x elements [8i, 8i+8) of each row, which all
// belong to head h = i>>3; its 8 accumulator regs cover
// write_vec_heads[h][(i&7)*8 .. +8).
// Partials (m, l, acc[512]) per (b, sub-chunk) go to workspace.
// ---------------------------------------------------------------------------
__global__ __launch_bounds__(256) void salience_pass1(
    const float* __restrict__ x,
    const void* __restrict__ mask,
    const float* __restrict__ temp,
    const float* __restrict__ w_sal,
    const float* __restrict__ b_sal,
    const int* __restrict__ flag,
    float* __restrict__ ws_m,
    float* __restrict__ ws_l,
    float* __restrict__ ws_acc)
{
    const int b     = blockIdx.x >> 4;     // CH = 16
    const int chunk = blockIdx.x & 15;
    const int lane  = threadIdx.x & 63;
    const int wv    = threadIdx.x >> 6;
    const int h     = lane >> 3;

    const int byte_mask = *flag;
    const unsigned char* m8  = (const unsigned char*)mask;
    const int*           m32 = (const int*)mask;

    // Register-resident w_sal slice: w[j*8+hh] = w_sal[(8*lane+j)*8+hh],
    // i.e. 64 contiguous floats at w_sal + lane*64.
    float w[64];
    {
        const float4* wp = (const float4*)w_sal + (size_t)lane * 16;
        #pragma unroll
        for (int q = 0; q < 16; ++q) {
            float4 v = wp[q];
            w[q*4+0] = v.x; w[q*4+1] = v.y; w[q*4+2] = v.z; w[q*4+3] = v.w;
        }
    }
    const float bs = b_sal[h];
    const float tp = temp[h];
    const float sp = (tp > 20.0f) ? tp : log1pf(__expf(tp));
    const float invT = 1.0f / (sp + 0.3f);

    float m = -1e9f;   // matches reference masked fill; all-masked => sc = exp(0)
    float l = 0.0f;
    float acc[8];
    #pragma unroll
    for (int j = 0; j < 8; ++j) acc[j] = 0.0f;

    const int t0 = chunk * ROWS_PER_BLOCK + wv * ROWS_PER_WAVE;
    const float4* xr = (const float4*)(x + ((size_t)b * T_DIM + t0) * D_DIM)
                       + (size_t)lane * 2;
    const size_t mbase = (size_t)b * T_DIM + t0;

    for (int r = 0; r < ROWS_PER_WAVE; ++r) {
        const int mv = byte_mask ? (int)m8[mbase + r] : m32[mbase + r];
        float4 a0 = xr[0];
        float4 a1 = xr[1];
        xr += D_DIM / 4;

        float xv[8] = {a0.x, a0.y, a0.z, a0.w, a1.x, a1.y, a1.z, a1.w};

        // 8-head dot partials from this lane's 8 elements
        float p[8];
        #pragma unroll
        for (int hh = 0; hh < 8; ++hh) {
            float s = xv[0] * w[0*8 + hh];
            #pragma unroll
            for (int j = 1; j < 8; ++j) s = fmaf(xv[j], w[j*8 + hh], s);
            p[hh] = s;
        }
        // full butterfly reduce (all lanes end with all 8 head sums)
        #pragma unroll
        for (int s = 1; s < 64; s <<= 1) {
            #pragma unroll
            for (int hh = 0; hh < 8; ++hh) p[hh] += __shfl_xor(p[hh], s, 64);
        }
        // select this lane's head value (static-index cndmask tree)
        float t01 = (h & 1) ? p[1] : p[0];
        float t23 = (h & 1) ? p[3] : p[2];
        float t45 = (h & 1) ? p[5] : p[4];
        float t67 = (h & 1) ? p[7] : p[6];
        float u0  = (h & 2) ? t23 : t01;
        float u1  = (h & 2) ? t67 : t45;
        float sum = (h & 4) ? u1  : u0;

        const float lg = (sum + bs) * invT;
        const bool valid = (mv != 0);
        const float mn = valid ? fmaxf(m, lg) : m;
        const float sc = __expf(m - mn);            // exp(-huge) flushes to 0, no NaN
        const float pe = valid ? __expf(lg - mn) : 0.0f;
        l = l * sc + pe;
        #pragma unroll
        for (int j = 0; j < 8; ++j) acc[j] = acc[j] * sc + pe * xv[j];
        m = mn;
    }

    const int sub = chunk * 4 + wv;          // 0..63
    const size_t bc = (size_t)b * SUBS + sub;
    if ((lane & 7) == 0) {
        ws_m[bc * H_DIM + h] = m;
        ws_l[bc * H_DIM + h] = l;
    }
    // acc element e = 8*lane + j == h*64 + (lane&7)*8 + j  -> store at bc*512 + e
    float4* dst = (float4*)(ws_acc + bc * D_DIM + (size_t)lane * 8);
    dst[0] = make_float4(acc[0], acc[1], acc[2], acc[3]);
    dst[1] = make_float4(acc[4], acc[5], acc[6], acc[7]);
}

// ---------------------------------------------------------------------------
// K2: combine 64 sub-chunk partials per (b,h), gate sigmoid, RMS norm, store
// all three outputs. One block per b, 512 threads (thread d = output dim;
// wave w == head h).
// ---------------------------------------------------------------------------
__global__ __launch_bounds__(512) void salience_pass2(
    const float* __restrict__ ws_m,
    const float* __restrict__ ws_l,
    const float* __restrict__ ws_acc,
    const float* __restrict__ w_gate,
    const float* __restrict__ b_gate,
    const float* __restrict__ scale,
    float* __restrict__ out)
{
    const int b  = blockIdx.x;
    const int d  = threadIdx.x;
    const int h  = d >> 6;
    const int dd = d & 63;

    float M = -3.0e38f;
    for (int c = 0; c < SUBS; ++c)
        M = fmaxf(M, ws_m[((size_t)b * SUBS + c) * H_DIM + h]);

    float A = 0.0f, L = 0.0f;
    for (int c = 0; c < SUBS; ++c) {
        const size_t bc = (size_t)b * SUBS + c;
        const float e = __expf(ws_m[bc * H_DIM + h] - M);
        L += ws_l[bc * H_DIM + h] * e;
        A += ws_acc[bc * D_DIM + d] * e;
    }
    const float wv = A / (L + 1e-6f);

    // gate: dot(wv_head, w_gate) within the wave (= head)
    float g = wv * w_gate[dd];
    #pragma unroll
    for (int s = 1; s < 64; s <<= 1) g += __shfl_xor(g, s, 64);
    const float gl = g + b_gate[0];
    const float u = (L > 0.0f) ? (1.0f / (1.0f + __expf(-gl))) : 0.0f;

    // RMS over the full 512-dim write_vec
    __shared__ float red[H_DIM];
    float sq = wv * wv;
    #pragma unroll
    for (int s = 1; s < 64; s <<= 1) sq += __shfl_xor(sq, s, 64);
    if (dd == 0) red[h] = sq;
    __syncthreads();
    float ssum = 0.0f;
    #pragma unroll
    for (int k = 0; k < H_DIM; ++k) ssum += red[k];
    const float rms = sqrtf(ssum * (1.0f / (float)D_DIM) + 1e-6f);

    out[(size_t)b * D_DIM + d] = wv / rms * scale[d];
    out[(size_t)B_DIM * D_DIM + (size_t)b * D_DIM + d] = u;
    if (dd == 0) out[2 * (size_t)B_DIM * D_DIM + (size_t)b * H_DIM + h] = u;
}

// ---------------------------------------------------------------------------
extern "C" void kernel_launch(void* const* d_in, const int* in_sizes, int n_in,
                              void* d_out, int out_size, void* d_ws, size_t ws_size,
                              hipStream_t stream) {
    (void)in_sizes; (void)n_in; (void)out_size; (void)ws_size;
    const float* x      = (const float*)d_in[0];
    const void*  mask   = d_in[1];
    const float* temp   = (const float*)d_in[2];
    const float* w_sal  = (const float*)d_in[3];
    const float* b_sal  = (const float*)d_in[4];
    const float* w_gate = (const float*)d_in[5];
    const float* b_gate = (const float*)d_in[6];
    const float* scale  = (const float*)d_in[7];
    float* out = (float*)d_out;

    char* ws = (char*)d_ws;
    int*   flag   = (int*)ws;
    float* ws_m   = (float*)(ws + 256);                         // B*64*8 floats
    float* ws_l   = (float*)(ws + 256 + 262144);                // B*64*8 floats
    float* ws_acc = (float*)(ws + 256 + 2 * 262144);            // B*64*512 floats

    detect_mask_kernel<<<1, 1024, 0, stream>>>((const int*)mask, flag);
    salience_pass1<<<B_DIM * CH, 256, 0, stream>>>(
        x, mask, temp, w_sal, b_sal, flag, ws_m, ws_l, ws_acc);
    salience_pass2<<<B_DIM, 512, 0, stream>>>(
        ws_m, ws_l, ws_acc, w_gate, b_gate, scale, out);
}

// Round 2
// 127.119 us; speedup vs baseline: 1.4277x; 1.4277x over previous
//
#include <hip/hip_runtime.h>
#include <hip/hip_bf16.h>

// Problem constants
#define B_DIM 128
#define T_DIM 2048
#define D_DIM 512
#define H_DIM 8
#define HD_DIM 64
#define CH 8                        // chunks per batch row
#define ROWS_PER_BLOCK (T_DIM / CH) // 256
#define ROWS_PER_WAVE (ROWS_PER_BLOCK / 4) // 64 == wave size (ballot trick)
#define SUBS (CH * 4)               // 32 partials per b

// ---------------------------------------------------------------------------
// K0: detect whether mask buffer is 1-byte bool or 4-byte int32.
// ---------------------------------------------------------------------------
__global__ void detect_mask_kernel(const int* __restrict__ mask_as_int,
                                   int* __restrict__ flag) {
    __shared__ int any_big;
    if (threadIdx.x == 0) any_big = 0;
    __syncthreads();
    int local = 0;
    for (int i = threadIdx.x; i < 16384; i += blockDim.x) {
        unsigned v = (unsigned)mask_as_int[i];
        if (v > 1u) local = 1;
    }
    if (local) atomicOr(&any_big, 1);
    __syncthreads();
    if (threadIdx.x == 0) *flag = any_big;  // 1 => byte mask, 0 => int32 mask
}

// ---------------------------------------------------------------------------
// K1: single pass over x with online softmax (deferred-max) per (b, head).
// Wave = 64 rows. Lane i owns x[8i..8i+8) of each row (head h = i>>3).
// Dot reduction = reduce-scatter over lane bits 5..3 (head bits 2..0),
// then 3-stage intra-group butterfly. 10 shuffles/row total.
// ---------------------------------------------------------------------------
__global__ __launch_bounds__(256, 4) void salience_pass1(
    const float* __restrict__ x,
    const void* __restrict__ mask,
    const float* __restrict__ temp,
    const float* __restrict__ w_sal,
    const float* __restrict__ b_sal,
    const int* __restrict__ flag,
    float* __restrict__ ws_m,
    float* __restrict__ ws_l,
    float* __restrict__ ws_acc)
{
    const int b     = blockIdx.x >> 3;     // CH = 8
    const int chunk = blockIdx.x & 7;
    const int lane  = threadIdx.x & 63;
    const int wv    = threadIdx.x >> 6;
    const int h     = lane >> 3;

    const int byte_mask = *flag;

    // Register-resident w_sal slice: w[j*8+hh] = w_sal[(8*lane+j)*8+hh]
    // (64 contiguous floats at w_sal + lane*64).
    float w[64];
    {
        const float4* wp = (const float4*)w_sal + (size_t)lane * 16;
        #pragma unroll
        for (int q = 0; q < 16; ++q) {
            float4 v = wp[q];
            w[q*4+0] = v.x; w[q*4+1] = v.y; w[q*4+2] = v.z; w[q*4+3] = v.w;
        }
    }
    const float bs = b_sal[h];
    const float tp = temp[h];
    const float sp = (tp > 20.0f) ? tp : log1pf(__expf(tp));
    const float invT = 1.0f / (sp + 0.3f);

    const int t0 = chunk * ROWS_PER_BLOCK + wv * ROWS_PER_WAVE;
    const size_t mbase = (size_t)b * T_DIM + t0;

    // Mask prefetch: lane r loads row r's mask; one ballot -> 64-bit row mask.
    int mv = byte_mask ? (int)((const unsigned char*)mask)[mbase + lane]
                       : ((const int*)mask)[mbase + lane];
    const unsigned long long rowmask = __ballot(mv != 0);

    float m = -1e9f;   // matches reference masked fill
    float l = 0.0f;
    float acc[8];
    #pragma unroll
    for (int j = 0; j < 8; ++j) acc[j] = 0.0f;

    const float4* xr = (const float4*)(x + ((size_t)b * T_DIM + t0) * D_DIM)
                       + (size_t)lane * 2;
    float4 a0 = xr[0];
    float4 a1 = xr[1];

    for (int r = 0; r < ROWS_PER_WAVE; ++r) {
        // software prefetch next row (clamped on last iter; stays in bounds)
        const float4* xn = xr + ((r < ROWS_PER_WAVE - 1) ? (D_DIM / 4) : 0);
        float4 n0 = xn[0];
        float4 n1 = xn[1];
        xr = xn;

        const float xv[8] = {a0.x, a0.y, a0.z, a0.w, a1.x, a1.y, a1.z, a1.w};

        // 8-head dot partials from this lane's 8 elements
        float p[8];
        #pragma unroll
        for (int hh = 0; hh < 8; ++hh) {
            float s = xv[0] * w[0*8 + hh];
            #pragma unroll
            for (int j = 1; j < 8; ++j) s = fmaf(xv[j], w[j*8 + hh], s);
            p[hh] = s;
        }
        // Reduce-scatter: head bit k <-> lane bit k+3.
        const bool hi5 = (lane & 32) != 0;
        float q0 = (hi5 ? p[4] : p[0]) + __shfl_xor(hi5 ? p[0] : p[4], 32, 64);
        float q1 = (hi5 ? p[5] : p[1]) + __shfl_xor(hi5 ? p[1] : p[5], 32, 64);
        float q2 = (hi5 ? p[6] : p[2]) + __shfl_xor(hi5 ? p[2] : p[6], 32, 64);
        float q3 = (hi5 ? p[7] : p[3]) + __shfl_xor(hi5 ? p[3] : p[7], 32, 64);
        const bool hi4 = (lane & 16) != 0;
        float r0 = (hi4 ? q2 : q0) + __shfl_xor(hi4 ? q0 : q2, 16, 64);
        float r1 = (hi4 ? q3 : q1) + __shfl_xor(hi4 ? q1 : q3, 16, 64);
        const bool hi3 = (lane & 8) != 0;
        float s = (hi3 ? r1 : r0) + __shfl_xor(hi3 ? r0 : r1, 8, 64);
        // intra-group butterfly (all 8 lanes same head)
        s += __shfl_xor(s, 4, 64);
        s += __shfl_xor(s, 2, 64);
        s += __shfl_xor(s, 1, 64);
        // s == full dot for head (lane>>3)

        const bool valid = (rowmask >> r) & 1ull;
        const float lg  = (s + bs) * invT;
        const float lgv = valid ? lg : -1e9f;

        // Deferred-max: rescale only when overshoot would exceed e^8.
        const bool need = lgv > m + 8.0f;
        if (__any(need)) {
            const float mn = need ? lgv : m;
            const float sc = __expf(m - mn);   // flushes to 0 from -1e9 init
            l *= sc;
            #pragma unroll
            for (int j = 0; j < 8; ++j) acc[j] *= sc;
            m = mn;
        }
        const float pe = valid ? __expf(lgv - m) : 0.0f;  // <= e^8
        l += pe;
        #pragma unroll
        for (int j = 0; j < 8; ++j) acc[j] = fmaf(pe, xv[j], acc[j]);

        a0 = n0; a1 = n1;
    }

    const int sub = chunk * 4 + wv;          // 0..31
    const size_t bc = (size_t)b * SUBS + sub;
    if ((lane & 7) == 0) {
        ws_m[bc * H_DIM + h] = m;
        ws_l[bc * H_DIM + h] = l;
    }
    // acc element e = 8*lane + j  -> store at bc*512 + e
    float4* dst = (float4*)(ws_acc + bc * D_DIM + (size_t)lane * 8);
    dst[0] = make_float4(acc[0], acc[1], acc[2], acc[3]);
    dst[1] = make_float4(acc[4], acc[5], acc[6], acc[7]);
}

// ---------------------------------------------------------------------------
// K2: combine 32 sub-chunk partials per (b,h), gate sigmoid, RMS norm, store
// all three outputs. One block per b, 512 threads (thread d = output dim;
// wave == head).
// ---------------------------------------------------------------------------
__global__ __launch_bounds__(512) void salience_pass2(
    const float* __restrict__ ws_m,
    const float* __restrict__ ws_l,
    const float* __restrict__ ws_acc,
    const float* __restrict__ w_gate,
    const float* __restrict__ b_gate,
    const float* __restrict__ scale,
    float* __restrict__ out)
{
    const int b  = blockIdx.x;
    const int d  = threadIdx.x;
    const int h  = d >> 6;
    const int dd = d & 63;

    float M = -3.0e38f;
    for (int c = 0; c < SUBS; ++c)
        M = fmaxf(M, ws_m[((size_t)b * SUBS + c) * H_DIM + h]);

    float A = 0.0f, L = 0.0f;
    for (int c = 0; c < SUBS; ++c) {
        const size_t bc = (size_t)b * SUBS + c;
        const float e = __expf(ws_m[bc * H_DIM + h] - M);
        L += ws_l[bc * H_DIM + h] * e;
        A += ws_acc[bc * D_DIM + d] * e;
    }
    const float wv = A / (L + 1e-6f);

    // gate: dot(wv_head, w_gate) within the wave (= head)
    float g = wv * w_gate[dd];
    #pragma unroll
    for (int s = 1; s < 64; s <<= 1) g += __shfl_xor(g, s, 64);
    const float gl = g + b_gate[0];
    const float u = (L > 0.0f) ? (1.0f / (1.0f + __expf(-gl))) : 0.0f;

    // RMS over the full 512-dim write_vec
    __shared__ float red[H_DIM];
    float sq = wv * wv;
    #pragma unroll
    for (int s = 1; s < 64; s <<= 1) sq += __shfl_xor(sq, s, 64);
    if (dd == 0) red[h] = sq;
    __syncthreads();
    float ssum = 0.0f;
    #pragma unroll
    for (int k = 0; k < H_DIM; ++k) ssum += red[k];
    const float rms = sqrtf(ssum * (1.0f / (float)D_DIM) + 1e-6f);

    out[(size_t)b * D_DIM + d] = wv / rms * scale[d];
    out[(size_t)B_DIM * D_DIM + (size_t)b * D_DIM + d] = u;
    if (dd == 0) out[2 * (size_t)B_DIM * D_DIM + (size_t)b * H_DIM + h] = u;
}

// ---------------------------------------------------------------------------
extern "C" void kernel_launch(void* const* d_in, const int* in_sizes, int n_in,
                              void* d_out, int out_size, void* d_ws, size_t ws_size,
                              hipStream_t stream) {
    (void)in_sizes; (void)n_in; (void)out_size; (void)ws_size;
    const float* x      = (const float*)d_in[0];
    const void*  mask   = d_in[1];
    const float* temp   = (const float*)d_in[2];
    const float* w_sal  = (const float*)d_in[3];
    const float* b_sal  = (const float*)d_in[4];
    const float* w_gate = (const float*)d_in[5];
    const float* b_gate = (const float*)d_in[6];
    const float* scale  = (const float*)d_in[7];
    float* out = (float*)d_out;

    char* ws = (char*)d_ws;
    int*   flag   = (int*)ws;
    float* ws_m   = (float*)(ws + 256);                       // B*32*8 floats (128KB)
    float* ws_l   = (float*)(ws + 256 + 131072);              // B*32*8 floats
    float* ws_acc = (float*)(ws + 256 + 2 * 131072);          // B*32*512 floats (8MB)

    detect_mask_kernel<<<1, 1024, 0, stream>>>((const int*)mask, flag);
    salience_pass1<<<B_DIM * CH, 256, 0, stream>>>(
        x, mask, temp, w_sal, b_sal, flag, ws_m, ws_l, ws_acc);
    salience_pass2<<<B_DIM, 512, 0, stream>>>(
        ws_m, ws_l, ws_acc, w_gate, b_gate, scale, out);
}

// Round 3
// 120.965 us; speedup vs baseline: 1.5003x; 1.0509x over previous
//
#include <hip/hip_runtime.h>
#include <hip/hip_bf16.h>

// Problem constants
#define B_DIM 128
#define T_DIM 2048
#define D_DIM 512
#define H_DIM 8
#define HD_DIM 64
#define CH 8                        // chunks per batch row
#define ROWS_PER_BLOCK (T_DIM / CH) // 256
#define ROWS_PER_WAVE (ROWS_PER_BLOCK / 4) // 64 == wave size (ballot trick)
#define SUBS (CH * 4)               // 32 partials per b

typedef float f4v __attribute__((ext_vector_type(4)));

__device__ __forceinline__ f4v ntld(const f4v* p) {
    return __builtin_nontemporal_load(p);
}

// ---------------------------------------------------------------------------
// K0: detect whether mask buffer is 1-byte bool or 4-byte int32.
// Reads 4096 int32 (16 KB). For a byte-packed 0/1 mask, each word is >1 with
// p=7/8 -> p(undetected) ~ (1/8)^4096: deterministic for this input.
// ---------------------------------------------------------------------------
__global__ void detect_mask_kernel(const int* __restrict__ mask_as_int,
                                   int* __restrict__ flag) {
    __shared__ int any_big;
    if (threadIdx.x == 0) any_big = 0;
    __syncthreads();
    int local = 0;
    for (int i = threadIdx.x; i < 4096; i += blockDim.x) {
        unsigned v = (unsigned)mask_as_int[i];
        if (v > 1u) local = 1;
    }
    if (local) atomicOr(&any_big, 1);
    __syncthreads();
    if (threadIdx.x == 0) *flag = any_big;  // 1 => byte mask, 0 => int32 mask
}

// ---------------------------------------------------------------------------
// K1: single pass over x with online softmax (deferred-max) per (b, head).
// Wave = 64 rows. Lane i owns x[8i..8i+8) of each row (head h = i>>3).
// Reduce-scatter over lane bits 5..3 then intra-group butterfly: 10 shfl/row.
// Prefetch depth 2 (two rotating register buffers), nontemporal x stream.
// ---------------------------------------------------------------------------
__global__ __launch_bounds__(256, 4) void salience_pass1(
    const float* __restrict__ x,
    const void* __restrict__ mask,
    const float* __restrict__ temp,
    const float* __restrict__ w_sal,
    const float* __restrict__ b_sal,
    const int* __restrict__ flag,
    float* __restrict__ ws_m,
    float* __restrict__ ws_l,
    float* __restrict__ ws_acc)
{
    const int b     = blockIdx.x >> 3;     // CH = 8
    const int chunk = blockIdx.x & 7;
    const int lane  = threadIdx.x & 63;
    const int wv    = threadIdx.x >> 6;
    const int h     = lane >> 3;

    const int byte_mask = *flag;

    // Register-resident w_sal slice: w[j*8+hh] = w_sal[(8*lane+j)*8+hh]
    // (64 contiguous floats at w_sal + lane*64).
    float w[64];
    {
        const float4* wp = (const float4*)w_sal + (size_t)lane * 16;
        #pragma unroll
        for (int q = 0; q < 16; ++q) {
            float4 v = wp[q];
            w[q*4+0] = v.x; w[q*4+1] = v.y; w[q*4+2] = v.z; w[q*4+3] = v.w;
        }
    }
    const float bs = b_sal[h];
    const float tp = temp[h];
    const float sp = (tp > 20.0f) ? tp : log1pf(__expf(tp));
    const float invT = 1.0f / (sp + 0.3f);

    const int t0 = chunk * ROWS_PER_BLOCK + wv * ROWS_PER_WAVE;
    const size_t mbase = (size_t)b * T_DIM + t0;

    // Mask prefetch: lane r loads row r's mask; one ballot -> 64-bit row mask.
    int mv = byte_mask ? (int)((const unsigned char*)mask)[mbase + lane]
                       : ((const int*)mask)[mbase + lane];
    const unsigned long long rowmask = __ballot(mv != 0);

    float m = -1e9f;   // matches reference masked fill
    float l = 0.0f;
    float acc[8];
    #pragma unroll
    for (int j = 0; j < 8; ++j) acc[j] = 0.0f;

    const f4v* xbase = (const f4v*)(x + ((size_t)b * T_DIM + t0) * D_DIM)
                       + (size_t)lane * 2;

    // Prefetch rows 0 and 1 (depth-2 rotating buffers).
    f4v buf[2][2];
    buf[0][0] = ntld(xbase + 0);
    buf[0][1] = ntld(xbase + 1);
    buf[1][0] = ntld(xbase + (D_DIM / 4));
    buf[1][1] = ntld(xbase + (D_DIM / 4) + 1);

    #pragma unroll 2
    for (int r = 0; r < ROWS_PER_WAVE; ++r) {
        const int pi = r & 1;                 // static under unroll-2
        const f4v a0 = buf[pi][0];
        const f4v a1 = buf[pi][1];
        const float xv[8] = {a0.x, a0.y, a0.z, a0.w, a1.x, a1.y, a1.z, a1.w};

        // Re-issue this buffer for row r+2 (clamped; dup load L1-hits at tail).
        const int pr = (r + 2 < ROWS_PER_WAVE) ? (r + 2) : (ROWS_PER_WAVE - 1);
        const f4v* pp = xbase + (size_t)pr * (D_DIM / 4);
        buf[pi][0] = ntld(pp);
        buf[pi][1] = ntld(pp + 1);

        // 8-head dot partials from this lane's 8 elements
        float p[8];
        #pragma unroll
        for (int hh = 0; hh < 8; ++hh) {
            float s = xv[0] * w[0*8 + hh];
            #pragma unroll
            for (int j = 1; j < 8; ++j) s = fmaf(xv[j], w[j*8 + hh], s);
            p[hh] = s;
        }
        // Reduce-scatter: head bit k <-> lane bit k+3.
        const bool hi5 = (lane & 32) != 0;
        float q0 = (hi5 ? p[4] : p[0]) + __shfl_xor(hi5 ? p[0] : p[4], 32, 64);
        float q1 = (hi5 ? p[5] : p[1]) + __shfl_xor(hi5 ? p[1] : p[5], 32, 64);
        float q2 = (hi5 ? p[6] : p[2]) + __shfl_xor(hi5 ? p[2] : p[6], 32, 64);
        float q3 = (hi5 ? p[7] : p[3]) + __shfl_xor(hi5 ? p[3] : p[7], 32, 64);
        const bool hi4 = (lane & 16) != 0;
        float r0 = (hi4 ? q2 : q0) + __shfl_xor(hi4 ? q0 : q2, 16, 64);
        float r1 = (hi4 ? q3 : q1) + __shfl_xor(hi4 ? q1 : q3, 16, 64);
        const bool hi3 = (lane & 8) != 0;
        float s = (hi3 ? r1 : r0) + __shfl_xor(hi3 ? r0 : r1, 8, 64);
        // intra-group butterfly (all 8 lanes same head)
        s += __shfl_xor(s, 4, 64);
        s += __shfl_xor(s, 2, 64);
        s += __shfl_xor(s, 1, 64);
        // s == full dot for head (lane>>3)

        const bool valid = (rowmask >> r) & 1ull;
        const float lg  = (s + bs) * invT;
        const float lgv = valid ? lg : -1e9f;

        // Deferred-max: rescale only when overshoot would exceed e^8.
        const bool need = lgv > m + 8.0f;
        if (__any(need)) {
            const float mn = need ? lgv : m;
            const float sc = __expf(m - mn);   // flushes to 0 from -1e9 init
            l *= sc;
            #pragma unroll
            for (int j = 0; j < 8; ++j) acc[j] *= sc;
            m = mn;
        }
        const float pe = valid ? __expf(lgv - m) : 0.0f;  // <= e^8
        l += pe;
        #pragma unroll
        for (int j = 0; j < 8; ++j) acc[j] = fmaf(pe, xv[j], acc[j]);
    }

    const int sub = chunk * 4 + wv;          // 0..31
    const size_t bc = (size_t)b * SUBS + sub;
    if ((lane & 7) == 0) {
        ws_m[bc * H_DIM + h] = m;
        ws_l[bc * H_DIM + h] = l;
    }
    // acc element e = 8*lane + j  -> store at bc*512 + e
    float4* dst = (float4*)(ws_acc + bc * D_DIM + (size_t)lane * 8);
    dst[0] = make_float4(acc[0], acc[1], acc[2], acc[3]);
    dst[1] = make_float4(acc[4], acc[5], acc[6], acc[7]);
}

// ---------------------------------------------------------------------------
// K2: combine 32 sub-chunk partials per (b,h), gate sigmoid, RMS norm, store
// all three outputs. One block per b, 512 threads (thread d = output dim;
// wave == head).
// ---------------------------------------------------------------------------
__global__ __launch_bounds__(512) void salience_pass2(
    const float* __restrict__ ws_m,
    const float* __restrict__ ws_l,
    const float* __restrict__ ws_acc,
    const float* __restrict__ w_gate,
    const float* __restrict__ b_gate,
    const float* __restrict__ scale,
    float* __restrict__ out)
{
    const int b  = blockIdx.x;
    const int d  = threadIdx.x;
    const int h  = d >> 6;
    const int dd = d & 63;

    float M = -3.0e38f;
    for (int c = 0; c < SUBS; ++c)
        M = fmaxf(M, ws_m[((size_t)b * SUBS + c) * H_DIM + h]);

    float A = 0.0f, L = 0.0f;
    for (int c = 0; c < SUBS; ++c) {
        const size_t bc = (size_t)b * SUBS + c;
        const float e = __expf(ws_m[bc * H_DIM + h] - M);
        L += ws_l[bc * H_DIM + h] * e;
        A += ws_acc[bc * D_DIM + d] * e;
    }
    const float wv = A / (L + 1e-6f);

    // gate: dot(wv_head, w_gate) within the wave (= head)
    float g = wv * w_gate[dd];
    #pragma unroll
    for (int s = 1; s < 64; s <<= 1) g += __shfl_xor(g, s, 64);
    const float gl = g + b_gate[0];
    const float u = (L > 0.0f) ? (1.0f / (1.0f + __expf(-gl))) : 0.0f;

    // RMS over the full 512-dim write_vec
    __shared__ float red[H_DIM];
    float sq = wv * wv;
    #pragma unroll
    for (int s = 1; s < 64; s <<= 1) sq += __shfl_xor(sq, s, 64);
    if (dd == 0) red[h] = sq;
    __syncthreads();
    float ssum = 0.0f;
    #pragma unroll
    for (int k = 0; k < H_DIM; ++k) ssum += red[k];
    const float rms = sqrtf(ssum * (1.0f / (float)D_DIM) + 1e-6f);

    out[(size_t)b * D_DIM + d] = wv / rms * scale[d];
    out[(size_t)B_DIM * D_DIM + (size_t)b * D_DIM + d] = u;
    if (dd == 0) out[2 * (size_t)B_DIM * D_DIM + (size_t)b * H_DIM + h] = u;
}

// ---------------------------------------------------------------------------
extern "C" void kernel_launch(void* const* d_in, const int* in_sizes, int n_in,
                              void* d_out, int out_size, void* d_ws, size_t ws_size,
                              hipStream_t stream) {
    (void)in_sizes; (void)n_in; (void)out_size; (void)ws_size;
    const float* x      = (const float*)d_in[0];
    const void*  mask   = d_in[1];
    const float* temp   = (const float*)d_in[2];
    const float* w_sal  = (const float*)d_in[3];
    const float* b_sal  = (const float*)d_in[4];
    const float* w_gate = (const float*)d_in[5];
    const float* b_gate = (const float*)d_in[6];
    const float* scale  = (const float*)d_in[7];
    float* out = (float*)d_out;

    char* ws = (char*)d_ws;
    int*   flag   = (int*)ws;
    float* ws_m   = (float*)(ws + 256);                       // B*32*8 floats (128KB)
    float* ws_l   = (float*)(ws + 256 + 131072);              // B*32*8 floats
    float* ws_acc = (float*)(ws + 256 + 2 * 131072);          // B*32*512 floats (8MB)

    detect_mask_kernel<<<1, 256, 0, stream>>>((const int*)mask, flag);
    salience_pass1<<<B_DIM * CH, 256, 0, stream>>>(
        x, mask, temp, w_sal, b_sal, flag, ws_m, ws_l, ws_acc);
    salience_pass2<<<B_DIM, 512, 0, stream>>>(
        ws_m, ws_l, ws_acc, w_gate, b_gate, scale, out);
}

// Round 4
// 119.057 us; speedup vs baseline: 1.5244x; 1.0160x over previous
//
#include <hip/hip_runtime.h>

// Problem constants
#define B_DIM 128
#define T_DIM 2048
#define D_DIM 512
#define H_DIM 8
#define HD_DIM 64
#define CH 8                        // chunks per batch row
#define ROWS_PER_BLOCK (T_DIM / CH) // 256
#define ROWS_PER_WAVE (ROWS_PER_BLOCK / 4) // 64 == wave size (ballot trick)
#define SUBS (CH * 4)               // 32 partials per b

typedef float f4v __attribute__((ext_vector_type(4)));

// ---------------------------------------------------------------------------
// K0: detect whether mask buffer is 1-byte bool or 4-byte int32.
// 64 threads read 64 int32 (256 B). For a byte-packed 0/1 mask each word is
// >1 with p=7/8 -> p(undetected) ~ (1/8)^64 ~ 1e-58: deterministic here.
// ---------------------------------------------------------------------------
__global__ void detect_mask_kernel(const int* __restrict__ mask_as_int,
                                   int* __restrict__ flag) {
    const unsigned v = (unsigned)mask_as_int[threadIdx.x];
    const unsigned long long bb = __ballot(v > 1u);
    if (threadIdx.x == 0) *flag = (bb != 0ull) ? 1 : 0;
}

// ---------------------------------------------------------------------------
// K1: single pass over x with online softmax (deferred-max) per (b, head).
// Wave = 64 rows. Lane i owns x[8i..8i+8) of each row (head h = i>>3).
// Reduce-scatter over lane bits 5..3 then intra-group butterfly: 10 shfl/row.
// Depth-2 prefetch with NAMED buffers, no xv copy (prefetch issued after the
// buffer's last use) -> ~114 VGPR, spill-free at 4 waves/SIMD.
// ---------------------------------------------------------------------------
#define ROW_BODY(ROW, B0, B1)                                                  \
  {                                                                            \
    const int row_ = (ROW);                                                    \
    /* 8-head dot partials from this lane's 8 elements (in B0/B1) */           \
    float p0 = B0.x * w[0];                                                    \
    float p1 = B0.x * w[1];                                                    \
    float p2 = B0.x * w[2];                                                    \
    float p3 = B0.x * w[3];                                                    \
    float p4 = B0.x * w[4];                                                    \
    float p5 = B0.x * w[5];                                                    \
    float p6 = B0.x * w[6];                                                    \
    float p7 = B0.x * w[7];                                                    \
    p0 = fmaf(B0.y, w[8+0], p0);  p1 = fmaf(B0.y, w[8+1], p1);                 \
    p2 = fmaf(B0.y, w[8+2], p2);  p3 = fmaf(B0.y, w[8+3], p3);                 \
    p4 = fmaf(B0.y, w[8+4], p4);  p5 = fmaf(B0.y, w[8+5], p5);                 \
    p6 = fmaf(B0.y, w[8+6], p6);  p7 = fmaf(B0.y, w[8+7], p7);                 \
    p0 = fmaf(B0.z, w[16+0], p0); p1 = fmaf(B0.z, w[16+1], p1);                \
    p2 = fmaf(B0.z, w[16+2], p2); p3 = fmaf(B0.z, w[16+3], p3);                \
    p4 = fmaf(B0.z, w[16+4], p4); p5 = fmaf(B0.z, w[16+5], p5);                \
    p6 = fmaf(B0.z, w[16+6], p6); p7 = fmaf(B0.z, w[16+7], p7);                \
    p0 = fmaf(B0.w, w[24+0], p0); p1 = fmaf(B0.w, w[24+1], p1);                \
    p2 = fmaf(B0.w, w[24+2], p2); p3 = fmaf(B0.w, w[24+3], p3);                \
    p4 = fmaf(B0.w, w[24+4], p4); p5 = fmaf(B0.w, w[24+5], p5);                \
    p6 = fmaf(B0.w, w[24+6], p6); p7 = fmaf(B0.w, w[24+7], p7);                \
    p0 = fmaf(B1.x, w[32+0], p0); p1 = fmaf(B1.x, w[32+1], p1);                \
    p2 = fmaf(B1.x, w[32+2], p2); p3 = fmaf(B1.x, w[32+3], p3);                \
    p4 = fmaf(B1.x, w[32+4], p4); p5 = fmaf(B1.x, w[32+5], p5);                \
    p6 = fmaf(B1.x, w[32+6], p6); p7 = fmaf(B1.x, w[32+7], p7);                \
    p0 = fmaf(B1.y, w[40+0], p0); p1 = fmaf(B1.y, w[40+1], p1);                \
    p2 = fmaf(B1.y, w[40+2], p2); p3 = fmaf(B1.y, w[40+3], p3);                \
    p4 = fmaf(B1.y, w[40+4], p4); p5 = fmaf(B1.y, w[40+5], p5);                \
    p6 = fmaf(B1.y, w[40+6], p6); p7 = fmaf(B1.y, w[40+7], p7);                \
    p0 = fmaf(B1.z, w[48+0], p0); p1 = fmaf(B1.z, w[48+1], p1);                \
    p2 = fmaf(B1.z, w[48+2], p2); p3 = fmaf(B1.z, w[48+3], p3);                \
    p4 = fmaf(B1.z, w[48+4], p4); p5 = fmaf(B1.z, w[48+5], p5);                \
    p6 = fmaf(B1.z, w[48+6], p6); p7 = fmaf(B1.z, w[48+7], p7);                \
    p0 = fmaf(B1.w, w[56+0], p0); p1 = fmaf(B1.w, w[56+1], p1);                \
    p2 = fmaf(B1.w, w[56+2], p2); p3 = fmaf(B1.w, w[56+3], p3);                \
    p4 = fmaf(B1.w, w[56+4], p4); p5 = fmaf(B1.w, w[56+5], p5);                \
    p6 = fmaf(B1.w, w[56+6], p6); p7 = fmaf(B1.w, w[56+7], p7);                \
    /* Reduce-scatter: head bit k <-> lane bit k+3 */                          \
    const bool hi5 = (lane & 32) != 0;                                         \
    float q0 = (hi5 ? p4 : p0) + __shfl_xor(hi5 ? p0 : p4, 32, 64);            \
    float q1 = (hi5 ? p5 : p1) + __shfl_xor(hi5 ? p1 : p5, 32, 64);            \
    float q2 = (hi5 ? p6 : p2) + __shfl_xor(hi5 ? p2 : p6, 32, 64);            \
    float q3 = (hi5 ? p7 : p3) + __shfl_xor(hi5 ? p3 : p7, 32, 64);            \
    const bool hi4 = (lane & 16) != 0;                                         \
    float r0 = (hi4 ? q2 : q0) + __shfl_xor(hi4 ? q0 : q2, 16, 64);            \
    float r1 = (hi4 ? q3 : q1) + __shfl_xor(hi4 ? q1 : q3, 16, 64);            \
    const bool hi3 = (lane & 8) != 0;                                          \
    float s = (hi3 ? r1 : r0) + __shfl_xor(hi3 ? r0 : r1, 8, 64);              \
    s += __shfl_xor(s, 4, 64);                                                 \
    s += __shfl_xor(s, 2, 64);                                                 \
    s += __shfl_xor(s, 1, 64);                                                 \
    const bool valid = (rowmask >> row_) & 1ull;                               \
    const float lg  = (s + bs) * invT;                                         \
    const float lgv = valid ? lg : -1e9f;                                      \
    const bool need = lgv > m + 8.0f;                                          \
    if (__any(need)) {                                                         \
      const float mn = need ? lgv : m;                                         \
      const float sc = __expf(m - mn);                                         \
      l *= sc;                                                                 \
      acc0 *= sc; acc1 *= sc; acc2 *= sc; acc3 *= sc;                          \
      acc4 *= sc; acc5 *= sc; acc6 *= sc; acc7 *= sc;                          \
      m = mn;                                                                  \
    }                                                                          \
    const float pe = valid ? __expf(lgv - m) : 0.0f;                           \
    l += pe;                                                                   \
    acc0 = fmaf(pe, B0.x, acc0); acc1 = fmaf(pe, B0.y, acc1);                  \
    acc2 = fmaf(pe, B0.z, acc2); acc3 = fmaf(pe, B0.w, acc3);                  \
    acc4 = fmaf(pe, B1.x, acc4); acc5 = fmaf(pe, B1.y, acc5);                  \
    acc6 = fmaf(pe, B1.z, acc6); acc7 = fmaf(pe, B1.w, acc7);                  \
    /* prefetch row_+2 into this buffer (clamped dup at tail, L1-hit) */       \
    const int pr_ = (row_ + 2 < ROWS_PER_WAVE) ? (row_ + 2)                    \
                                               : (ROWS_PER_WAVE - 1);          \
    const f4v* pp_ = xbase + (size_t)pr_ * (D_DIM / 4);                        \
    B0 = pp_[0];                                                               \
    B1 = pp_[1];                                                               \
  }

__global__ __launch_bounds__(256, 4) void salience_pass1(
    const float* __restrict__ x,
    const void* __restrict__ mask,
    const float* __restrict__ temp,
    const float* __restrict__ w_sal,
    const float* __restrict__ b_sal,
    const int* __restrict__ flag,
    float* __restrict__ ws_m,
    float* __restrict__ ws_l,
    float* __restrict__ ws_acc)
{
    const int b     = blockIdx.x >> 3;     // CH = 8
    const int chunk = blockIdx.x & 7;
    const int lane  = threadIdx.x & 63;
    const int wv    = threadIdx.x >> 6;
    const int h     = lane >> 3;

    const int byte_mask = *flag;

    // Register-resident w_sal slice: w[j*8+hh] = w_sal[(8*lane+j)*8+hh]
    float w[64];
    {
        const float4* wp = (const float4*)w_sal + (size_t)lane * 16;
        #pragma unroll
        for (int q = 0; q < 16; ++q) {
            float4 v = wp[q];
            w[q*4+0] = v.x; w[q*4+1] = v.y; w[q*4+2] = v.z; w[q*4+3] = v.w;
        }
    }
    const float bs = b_sal[h];
    const float tp = temp[h];
    const float sp = (tp > 20.0f) ? tp : log1pf(__expf(tp));
    const float invT = 1.0f / (sp + 0.3f);

    const int t0 = chunk * ROWS_PER_BLOCK + wv * ROWS_PER_WAVE;
    const size_t mbase = (size_t)b * T_DIM + t0;

    // Mask prefetch: lane r loads row r's mask; one ballot -> 64-bit row mask.
    int mv = byte_mask ? (int)((const unsigned char*)mask)[mbase + lane]
                       : ((const int*)mask)[mbase + lane];
    const unsigned long long rowmask = __ballot(mv != 0);

    float m = -1e9f;   // matches reference masked fill
    float l = 0.0f;
    float acc0 = 0.f, acc1 = 0.f, acc2 = 0.f, acc3 = 0.f;
    float acc4 = 0.f, acc5 = 0.f, acc6 = 0.f, acc7 = 0.f;

    const f4v* xbase = (const f4v*)(x + ((size_t)b * T_DIM + t0) * D_DIM)
                       + (size_t)lane * 2;

    // Prologue: rows 0 and 1 into named buffers (depth-2).
    f4v bA0 = xbase[0];
    f4v bA1 = xbase[1];
    f4v bB0 = xbase[D_DIM / 4];
    f4v bB1 = xbase[D_DIM / 4 + 1];

    for (int r2 = 0; r2 < ROWS_PER_WAVE / 2; ++r2) {
        ROW_BODY(2 * r2,     bA0, bA1)
        ROW_BODY(2 * r2 + 1, bB0, bB1)
    }

    const int sub = chunk * 4 + wv;          // 0..31
    const size_t bc = (size_t)b * SUBS + sub;
    if ((lane & 7) == 0) {
        ws_m[bc * H_DIM + h] = m;
        ws_l[bc * H_DIM + h] = l;
    }
    float4* dst = (float4*)(ws_acc + bc * D_DIM + (size_t)lane * 8);
    dst[0] = make_float4(acc0, acc1, acc2, acc3);
    dst[1] = make_float4(acc4, acc5, acc6, acc7);
}

// ---------------------------------------------------------------------------
// K2: combine 32 sub-chunk partials per (b,h). Per-head stats via wave
// shuffle reduce into LDS e-factors, then the A-loop as 4 batches of 8
// independent global loads (explicit ILP). One block per b, 512 threads.
// ---------------------------------------------------------------------------
__global__ __launch_bounds__(512) void salience_pass2(
    const float* __restrict__ ws_m,
    const float* __restrict__ ws_l,
    const float* __restrict__ ws_acc,
    const float* __restrict__ w_gate,
    const float* __restrict__ b_gate,
    const float* __restrict__ scale,
    float* __restrict__ out)
{
    const int b  = blockIdx.x;
    const int d  = threadIdx.x;
    const int h  = d >> 6;       // wave == head
    const int dd = d & 63;
    const int lane = d & 63;

    __shared__ float sm_e[SUBS * H_DIM];
    __shared__ float sm_L[H_DIM];
    __shared__ float red[H_DIM];

    // Per-head stats: wave h, lanes 0..31 own c (32..63 duplicate).
    {
        const int c = lane & 31;
        const size_t idx = ((size_t)b * SUBS + c) * H_DIM + h;
        const float mv = ws_m[idx];
        const float lv = ws_l[idx];
        float M = mv;
        M = fmaxf(M, __shfl_xor(M, 16, 64));
        M = fmaxf(M, __shfl_xor(M, 8, 64));
        M = fmaxf(M, __shfl_xor(M, 4, 64));
        M = fmaxf(M, __shfl_xor(M, 2, 64));
        M = fmaxf(M, __shfl_xor(M, 1, 64));
        const float e = __expf(mv - M);
        float Lp = lv * e;
        Lp += __shfl_xor(Lp, 16, 64);
        Lp += __shfl_xor(Lp, 8, 64);
        Lp += __shfl_xor(Lp, 4, 64);
        Lp += __shfl_xor(Lp, 2, 64);
        Lp += __shfl_xor(Lp, 1, 64);
        if (lane < 32) sm_e[c * H_DIM + h] = e;
        if (lane == 0) sm_L[h] = Lp;
    }
    __syncthreads();

    // A = sum_c e[c][h] * ws_acc[b][c][d], batched 8-wide for ILP.
    float A = 0.0f;
    const float* pa = ws_acc + (size_t)b * SUBS * D_DIM + d;
    #pragma unroll
    for (int c0 = 0; c0 < SUBS; c0 += 8) {
        float v0 = pa[(size_t)(c0+0) * D_DIM];
        float v1 = pa[(size_t)(c0+1) * D_DIM];
        float v2 = pa[(size_t)(c0+2) * D_DIM];
        float v3 = pa[(size_t)(c0+3) * D_DIM];
        float v4 = pa[(size_t)(c0+4) * D_DIM];
        float v5 = pa[(size_t)(c0+5) * D_DIM];
        float v6 = pa[(size_t)(c0+6) * D_DIM];
        float v7 = pa[(size_t)(c0+7) * D_DIM];
        A = fmaf(sm_e[(c0+0) * H_DIM + h], v0, A);
        A = fmaf(sm_e[(c0+1) * H_DIM + h], v1, A);
        A = fmaf(sm_e[(c0+2) * H_DIM + h], v2, A);
        A = fmaf(sm_e[(c0+3) * H_DIM + h], v3, A);
        A = fmaf(sm_e[(c0+4) * H_DIM + h], v4, A);
        A = fmaf(sm_e[(c0+5) * H_DIM + h], v5, A);
        A = fmaf(sm_e[(c0+6) * H_DIM + h], v6, A);
        A = fmaf(sm_e[(c0+7) * H_DIM + h], v7, A);
    }
    const float L = sm_L[h];
    const float wv = A / (L + 1e-6f);

    // gate: dot(wv_head, w_gate) within the wave (= head)
    float g = wv * w_gate[dd];
    #pragma unroll
    for (int s = 1; s < 64; s <<= 1) g += __shfl_xor(g, s, 64);
    const float gl = g + b_gate[0];
    const float u = (L > 0.0f) ? (1.0f / (1.0f + __expf(-gl))) : 0.0f;

    // RMS over the full 512-dim write_vec
    float sq = wv * wv;
    #pragma unroll
    for (int s = 1; s < 64; s <<= 1) sq += __shfl_xor(sq, s, 64);
    if (dd == 0) red[h] = sq;
    __syncthreads();
    float ssum = 0.0f;
    #pragma unroll
    for (int k = 0; k < H_DIM; ++k) ssum += red[k];
    const float rms = sqrtf(ssum * (1.0f / (float)D_DIM) + 1e-6f);

    out[(size_t)b * D_DIM + d] = wv / rms * scale[d];
    out[(size_t)B_DIM * D_DIM + (size_t)b * D_DIM + d] = u;
    if (dd == 0) out[2 * (size_t)B_DIM * D_DIM + (size_t)b * H_DIM + h] = u;
}

// ---------------------------------------------------------------------------
extern "C" void kernel_launch(void* const* d_in, const int* in_sizes, int n_in,
                              void* d_out, int out_size, void* d_ws, size_t ws_size,
                              hipStream_t stream) {
    (void)in_sizes; (void)n_in; (void)out_size; (void)ws_size;
    const float* x      = (const float*)d_in[0];
    const void*  mask   = d_in[1];
    const float* temp   = (const float*)d_in[2];
    const float* w_sal  = (const float*)d_in[3];
    const float* b_sal  = (const float*)d_in[4];
    const float* w_gate = (const float*)d_in[5];
    const float* b_gate = (const float*)d_in[6];
    const float* scale  = (const float*)d_in[7];
    float* out = (float*)d_out;

    char* ws = (char*)d_ws;
    int*   flag   = (int*)ws;
    float* ws_m   = (float*)(ws + 256);                       // B*32*8 floats (128KB)
    float* ws_l   = (float*)(ws + 256 + 131072);              // B*32*8 floats
    float* ws_acc = (float*)(ws + 256 + 2 * 131072);          // B*32*512 floats (8MB)

    detect_mask_kernel<<<1, 64, 0, stream>>>((const int*)mask, flag);
    salience_pass1<<<B_DIM * CH, 256, 0, stream>>>(
        x, mask, temp, w_sal, b_sal, flag, ws_m, ws_l, ws_acc);
    salience_pass2<<<B_DIM, 512, 0, stream>>>(
        ws_m, ws_l, ws_acc, w_gate, b_gate, scale, out);
}

// Round 5
// 115.598 us; speedup vs baseline: 1.5700x; 1.0299x over previous
//
#include <hip/hip_runtime.h>

// Problem constants
#define B_DIM 128
#define T_DIM 2048
#define D_DIM 512
#define H_DIM 8
#define HD_DIM 64
#define CH 8                        // chunks per batch row
#define ROWS_PER_BLOCK (T_DIM / CH) // 256
#define ROWS_PER_WAVE (ROWS_PER_BLOCK / 4) // 64 == wave size (ballot trick)
#define SUBS (CH * 4)               // 32 partials per b

typedef float f4v __attribute__((ext_vector_type(4)));

// ---------------------------------------------------------------------------
// K1: single pass over x with online softmax (deferred-max) per (b, head).
// DENSE loads: lane i owns x[4i..4i+4) (head i>>4) and x[256+4i..+4)
// (head (i>>4)+4). Each of the row's two dwordx4 loads is a fully
// contiguous 1 KB wave access. Dual-head online state per lane.
// Reduce-scatter to head pairs: 14 shfl/row. Depth-2 named-buffer prefetch.
// Mask-format detection (byte vs int32) folded in via one ballot.
// ---------------------------------------------------------------------------
#define ROW_BODY(ROW, B0, B1)                                                  \
  {                                                                            \
    const int row_ = (ROW);                                                    \
    /* 8-head dot partials: elems 0-3 = B0 (wA = w[0..31]), 4-7 = B1 */        \
    float p0 = B0.x * w[0];                                                    \
    float p1 = B0.x * w[1];                                                    \
    float p2 = B0.x * w[2];                                                    \
    float p3 = B0.x * w[3];                                                    \
    float p4 = B0.x * w[4];                                                    \
    float p5 = B0.x * w[5];                                                    \
    float p6 = B0.x * w[6];                                                    \
    float p7 = B0.x * w[7];                                                    \
    p0 = fmaf(B0.y, w[8+0], p0);  p1 = fmaf(B0.y, w[8+1], p1);                 \
    p2 = fmaf(B0.y, w[8+2], p2);  p3 = fmaf(B0.y, w[8+3], p3);                 \
    p4 = fmaf(B0.y, w[8+4], p4);  p5 = fmaf(B0.y, w[8+5], p5);                 \
    p6 = fmaf(B0.y, w[8+6], p6);  p7 = fmaf(B0.y, w[8+7], p7);                 \
    p0 = fmaf(B0.z, w[16+0], p0); p1 = fmaf(B0.z, w[16+1], p1);                \
    p2 = fmaf(B0.z, w[16+2], p2); p3 = fmaf(B0.z, w[16+3], p3);                \
    p4 = fmaf(B0.z, w[16+4], p4); p5 = fmaf(B0.z, w[16+5], p5);                \
    p6 = fmaf(B0.z, w[16+6], p6); p7 = fmaf(B0.z, w[16+7], p7);                \
    p0 = fmaf(B0.w, w[24+0], p0); p1 = fmaf(B0.w, w[24+1], p1);                \
    p2 = fmaf(B0.w, w[24+2], p2); p3 = fmaf(B0.w, w[24+3], p3);                \
    p4 = fmaf(B0.w, w[24+4], p4); p5 = fmaf(B0.w, w[24+5], p5);                \
    p6 = fmaf(B0.w, w[24+6], p6); p7 = fmaf(B0.w, w[24+7], p7);                \
    p0 = fmaf(B1.x, w[32+0], p0); p1 = fmaf(B1.x, w[32+1], p1);                \
    p2 = fmaf(B1.x, w[32+2], p2); p3 = fmaf(B1.x, w[32+3], p3);                \
    p4 = fmaf(B1.x, w[32+4], p4); p5 = fmaf(B1.x, w[32+5], p5);                \
    p6 = fmaf(B1.x, w[32+6], p6); p7 = fmaf(B1.x, w[32+7], p7);                \
    p0 = fmaf(B1.y, w[40+0], p0); p1 = fmaf(B1.y, w[40+1], p1);                \
    p2 = fmaf(B1.y, w[40+2], p2); p3 = fmaf(B1.y, w[40+3], p3);                \
    p4 = fmaf(B1.y, w[40+4], p4); p5 = fmaf(B1.y, w[40+5], p5);                \
    p6 = fmaf(B1.y, w[40+6], p6); p7 = fmaf(B1.y, w[40+7], p7);                \
    p0 = fmaf(B1.z, w[48+0], p0); p1 = fmaf(B1.z, w[48+1], p1);                \
    p2 = fmaf(B1.z, w[48+2], p2); p3 = fmaf(B1.z, w[48+3], p3);                \
    p4 = fmaf(B1.z, w[48+4], p4); p5 = fmaf(B1.z, w[48+5], p5);                \
    p6 = fmaf(B1.z, w[48+6], p6); p7 = fmaf(B1.z, w[48+7], p7);                \
    p0 = fmaf(B1.w, w[56+0], p0); p1 = fmaf(B1.w, w[56+1], p1);                \
    p2 = fmaf(B1.w, w[56+2], p2); p3 = fmaf(B1.w, w[56+3], p3);                \
    p4 = fmaf(B1.w, w[56+4], p4); p5 = fmaf(B1.w, w[56+5], p5);                \
    p6 = fmaf(B1.w, w[56+6], p6); p7 = fmaf(B1.w, w[56+7], p7);                \
    /* Reduce-scatter to head pair {hA, hA+4}, hA = (lane>>4) = l5l4 */        \
    const bool hi5 = (lane & 32) != 0;   /* head bit 1 */                      \
    float q0 = (hi5 ? p2 : p0) + __shfl_xor(hi5 ? p0 : p2, 32, 64);            \
    float q1 = (hi5 ? p3 : p1) + __shfl_xor(hi5 ? p1 : p3, 32, 64);            \
    float q2 = (hi5 ? p6 : p4) + __shfl_xor(hi5 ? p4 : p6, 32, 64);            \
    float q3 = (hi5 ? p7 : p5) + __shfl_xor(hi5 ? p5 : p7, 32, 64);            \
    const bool hi4 = (lane & 16) != 0;   /* head bit 0 */                      \
    float sA = (hi4 ? q1 : q0) + __shfl_xor(hi4 ? q0 : q1, 16, 64);            \
    float sB = (hi4 ? q3 : q2) + __shfl_xor(hi4 ? q2 : q3, 16, 64);            \
    sA += __shfl_xor(sA, 8, 64);  sB += __shfl_xor(sB, 8, 64);                 \
    sA += __shfl_xor(sA, 4, 64);  sB += __shfl_xor(sB, 4, 64);                 \
    sA += __shfl_xor(sA, 2, 64);  sB += __shfl_xor(sB, 2, 64);                 \
    sA += __shfl_xor(sA, 1, 64);  sB += __shfl_xor(sB, 1, 64);                 \
    const bool valid = (rowmask >> row_) & 1ull;                               \
    const float lgA = valid ? (sA + bsA) * invTA : -1e9f;                      \
    const float lgB = valid ? (sB + bsB) * invTB : -1e9f;                      \
    const bool needA = lgA > mA + 8.0f;                                        \
    const bool needB = lgB > mB + 8.0f;                                        \
    if (__any(needA || needB)) {                                               \
      const float mnA = needA ? lgA : mA;                                      \
      const float scA = __expf(mA - mnA);                                      \
      const float mnB = needB ? lgB : mB;                                      \
      const float scB = __expf(mB - mnB);                                      \
      lA *= scA; lB *= scB;                                                    \
      acc0 *= scA; acc1 *= scA; acc2 *= scA; acc3 *= scA;                      \
      acc4 *= scB; acc5 *= scB; acc6 *= scB; acc7 *= scB;                      \
      mA = mnA; mB = mnB;                                                      \
    }                                                                          \
    const float peA = valid ? __expf(lgA - mA) : 0.0f;                         \
    const float peB = valid ? __expf(lgB - mB) : 0.0f;                         \
    lA += peA; lB += peB;                                                      \
    acc0 = fmaf(peA, B0.x, acc0); acc1 = fmaf(peA, B0.y, acc1);                \
    acc2 = fmaf(peA, B0.z, acc2); acc3 = fmaf(peA, B0.w, acc3);                \
    acc4 = fmaf(peB, B1.x, acc4); acc5 = fmaf(peB, B1.y, acc5);                \
    acc6 = fmaf(peB, B1.z, acc6); acc7 = fmaf(peB, B1.w, acc7);                \
    /* prefetch row_+2 into this buffer (clamped dup at tail, L1-hit) */       \
    const int pr_ = (row_ + 2 < ROWS_PER_WAVE) ? (row_ + 2)                    \
                                               : (ROWS_PER_WAVE - 1);          \
    const f4v* pp_ = xb + (size_t)pr_ * (D_DIM / 4);                           \
    B0 = pp_[0];                                                               \
    B1 = pp_[64];                                                              \
  }

__global__ __launch_bounds__(256, 4) void salience_pass1(
    const float* __restrict__ x,
    const void* __restrict__ mask,
    const float* __restrict__ temp,
    const float* __restrict__ w_sal,
    const float* __restrict__ b_sal,
    float* __restrict__ ws_m,
    float* __restrict__ ws_l,
    float* __restrict__ ws_acc)
{
    const int b     = blockIdx.x >> 3;     // CH = 8
    const int chunk = blockIdx.x & 7;
    const int lane  = threadIdx.x & 63;
    const int wv    = threadIdx.x >> 6;
    const int hA    = lane >> 4;           // lane's heads: hA and hA+4

    // Inline mask-format detection: byte-packed 0/1 mask -> some of the
    // first 64 int32 words are >1 with p = 1-(1/8)^64 (deterministic here).
    const unsigned mv0 = (unsigned)((const int*)mask)[lane];
    const int byte_mask = (__ballot(mv0 > 1u) != 0ull) ? 1 : 0;

    // Register-resident w_sal slice:
    //  w[j*8+hh] = w_sal[(4*lane+j)*8 + hh]        j=0..3  (elems 4i..4i+3)
    //  w[(4+j)*8+hh] = w_sal[(256+4*lane+j)*8+hh]  j=0..3  (elems 256+4i..)
    float w[64];
    {
        const float4* wa = (const float4*)(w_sal) + (size_t)lane * 8;
        const float4* wb = (const float4*)(w_sal + 2048) + (size_t)lane * 8;
        #pragma unroll
        for (int q = 0; q < 8; ++q) {
            float4 v = wa[q];
            w[q*4+0] = v.x; w[q*4+1] = v.y; w[q*4+2] = v.z; w[q*4+3] = v.w;
        }
        #pragma unroll
        for (int q = 0; q < 8; ++q) {
            float4 v = wb[q];
            w[32+q*4+0] = v.x; w[32+q*4+1] = v.y; w[32+q*4+2] = v.z; w[32+q*4+3] = v.w;
        }
    }
    const float bsA = b_sal[hA];
    const float bsB = b_sal[hA + 4];
    const float tpA = temp[hA];
    const float tpB = temp[hA + 4];
    const float spA = (tpA > 20.0f) ? tpA : log1pf(__expf(tpA));
    const float spB = (tpB > 20.0f) ? tpB : log1pf(__expf(tpB));
    const float invTA = 1.0f / (spA + 0.3f);
    const float invTB = 1.0f / (spB + 0.3f);

    const int t0 = chunk * ROWS_PER_BLOCK + wv * ROWS_PER_WAVE;
    const size_t mbase = (size_t)b * T_DIM + t0;

    // Mask prefetch: lane r loads row r's mask; one ballot -> 64-bit row mask.
    int mrow = byte_mask ? (int)((const unsigned char*)mask)[mbase + lane]
                         : ((const int*)mask)[mbase + lane];
    const unsigned long long rowmask = __ballot(mrow != 0);

    float mA = -1e9f, lA = 0.0f;
    float mB = -1e9f, lB = 0.0f;
    float acc0 = 0.f, acc1 = 0.f, acc2 = 0.f, acc3 = 0.f;
    float acc4 = 0.f, acc5 = 0.f, acc6 = 0.f, acc7 = 0.f;

    // Dense base: lane i -> f4v index i (bytes 16i) within each 1KB half-row.
    const f4v* xb = (const f4v*)(x + ((size_t)b * T_DIM + t0) * D_DIM) + lane;

    // Prologue: rows 0 and 1 into named buffers (depth-2).
    f4v bA0 = xb[0];
    f4v bA1 = xb[64];
    f4v bB0 = xb[128];
    f4v bB1 = xb[192];

    for (int r2 = 0; r2 < ROWS_PER_WAVE / 2; ++r2) {
        ROW_BODY(2 * r2,     bA0, bA1)
        ROW_BODY(2 * r2 + 1, bB0, bB1)
    }

    const int sub = chunk * 4 + wv;          // 0..31
    const size_t bc = (size_t)b * SUBS + sub;
    if ((lane & 15) == 0) {
        ws_m[bc * H_DIM + hA]     = mA;
        ws_m[bc * H_DIM + hA + 4] = mB;
        ws_l[bc * H_DIM + hA]     = lA;
        ws_l[bc * H_DIM + hA + 4] = lB;
    }
    // acc elems: A -> [4*lane, +4), B -> [256+4*lane, +4): dense stores.
    float4* dstA = (float4*)(ws_acc + bc * D_DIM) + lane;
    dstA[0]  = make_float4(acc0, acc1, acc2, acc3);
    dstA[64] = make_float4(acc4, acc5, acc6, acc7);
}

// ---------------------------------------------------------------------------
// K2: combine 32 sub-chunk partials per (b,h). Per-head stats via wave
// shuffle reduce into LDS e-factors, then the A-loop as 4 batches of 8
// independent global loads (explicit ILP). One block per b, 512 threads.
// ---------------------------------------------------------------------------
__global__ __launch_bounds__(512) void salience_pass2(
    const float* __restrict__ ws_m,
    const float* __restrict__ ws_l,
    const float* __restrict__ ws_acc,
    const float* __restrict__ w_gate,
    const float* __restrict__ b_gate,
    const float* __restrict__ scale,
    float* __restrict__ out)
{
    const int b  = blockIdx.x;
    const int d  = threadIdx.x;
    const int h  = d >> 6;       // wave == head
    const int dd = d & 63;
    const int lane = d & 63;

    __shared__ float sm_e[SUBS * H_DIM];
    __shared__ float sm_L[H_DIM];
    __shared__ float red[H_DIM];

    // Per-head stats: wave h, lanes 0..31 own c (32..63 duplicate).
    {
        const int c = lane & 31;
        const size_t idx = ((size_t)b * SUBS + c) * H_DIM + h;
        const float mv = ws_m[idx];
        const float lv = ws_l[idx];
        float M = mv;
        M = fmaxf(M, __shfl_xor(M, 16, 64));
        M = fmaxf(M, __shfl_xor(M, 8, 64));
        M = fmaxf(M, __shfl_xor(M, 4, 64));
        M = fmaxf(M, __shfl_xor(M, 2, 64));
        M = fmaxf(M, __shfl_xor(M, 1, 64));
        const float e = __expf(mv - M);
        float Lp = lv * e;
        Lp += __shfl_xor(Lp, 16, 64);
        Lp += __shfl_xor(Lp, 8, 64);
        Lp += __shfl_xor(Lp, 4, 64);
        Lp += __shfl_xor(Lp, 2, 64);
        Lp += __shfl_xor(Lp, 1, 64);
        if (lane < 32) sm_e[c * H_DIM + h] = e;
        if (lane == 0) sm_L[h] = Lp;
    }
    __syncthreads();

    // A = sum_c e[c][h] * ws_acc[b][c][d], batched 8-wide for ILP.
    float A = 0.0f;
    const float* pa = ws_acc + (size_t)b * SUBS * D_DIM + d;
    #pragma unroll
    for (int c0 = 0; c0 < SUBS; c0 += 8) {
        float v0 = pa[(size_t)(c0+0) * D_DIM];
        float v1 = pa[(size_t)(c0+1) * D_DIM];
        float v2 = pa[(size_t)(c0+2) * D_DIM];
        float v3 = pa[(size_t)(c0+3) * D_DIM];
        float v4 = pa[(size_t)(c0+4) * D_DIM];
        float v5 = pa[(size_t)(c0+5) * D_DIM];
        float v6 = pa[(size_t)(c0+6) * D_DIM];
        float v7 = pa[(size_t)(c0+7) * D_DIM];
        A = fmaf(sm_e[(c0+0) * H_DIM + h], v0, A);
        A = fmaf(sm_e[(c0+1) * H_DIM + h], v1, A);
        A = fmaf(sm_e[(c0+2) * H_DIM + h], v2, A);
        A = fmaf(sm_e[(c0+3) * H_DIM + h], v3, A);
        A = fmaf(sm_e[(c0+4) * H_DIM + h], v4, A);
        A = fmaf(sm_e[(c0+5) * H_DIM + h], v5, A);
        A = fmaf(sm_e[(c0+6) * H_DIM + h], v6, A);
        A = fmaf(sm_e[(c0+7) * H_DIM + h], v7, A);
    }
    const float L = sm_L[h];
    const float wv = A / (L + 1e-6f);

    // gate: dot(wv_head, w_gate) within the wave (= head)
    float g = wv * w_gate[dd];
    #pragma unroll
    for (int s = 1; s < 64; s <<= 1) g += __shfl_xor(g, s, 64);
    const float gl = g + b_gate[0];
    const float u = (L > 0.0f) ? (1.0f / (1.0f + __expf(-gl))) : 0.0f;

    // RMS over the full 512-dim write_vec
    float sq = wv * wv;
    #pragma unroll
    for (int s = 1; s < 64; s <<= 1) sq += __shfl_xor(sq, s, 64);
    if (dd == 0) red[h] = sq;
    __syncthreads();
    float ssum = 0.0f;
    #pragma unroll
    for (int k = 0; k < H_DIM; ++k) ssum += red[k];
    const float rms = sqrtf(ssum * (1.0f / (float)D_DIM) + 1e-6f);

    out[(size_t)b * D_DIM + d] = wv / rms * scale[d];
    out[(size_t)B_DIM * D_DIM + (size_t)b * D_DIM + d] = u;
    if (dd == 0) out[2 * (size_t)B_DIM * D_DIM + (size_t)b * H_DIM + h] = u;
}

// ---------------------------------------------------------------------------
extern "C" void kernel_launch(void* const* d_in, const int* in_sizes, int n_in,
                              void* d_out, int out_size, void* d_ws, size_t ws_size,
                              hipStream_t stream) {
    (void)in_sizes; (void)n_in; (void)out_size; (void)ws_size;
    const float* x      = (const float*)d_in[0];
    const void*  mask   = d_in[1];
    const float* temp   = (const float*)d_in[2];
    const float* w_sal  = (const float*)d_in[3];
    const float* b_sal  = (const float*)d_in[4];
    const float* w_gate = (const float*)d_in[5];
    const float* b_gate = (const float*)d_in[6];
    const float* scale  = (const float*)d_in[7];
    float* out = (float*)d_out;

    char* ws = (char*)d_ws;
    float* ws_m   = (float*)(ws + 256);                       // B*32*8 floats (128KB)
    float* ws_l   = (float*)(ws + 256 + 131072);              // B*32*8 floats
    float* ws_acc = (float*)(ws + 256 + 2 * 131072);          // B*32*512 floats (8MB)

    salience_pass1<<<B_DIM * CH, 256, 0, stream>>>(
        x, mask, temp, w_sal, b_sal, ws_m, ws_l, ws_acc);
    salience_pass2<<<B_DIM, 512, 0, stream>>>(
        ws_m, ws_l, ws_acc, w_gate, b_gate, scale, out);
}